// Round 1
// 1241.077 us; speedup vs baseline: 1.1263x; 1.1263x over previous
//
#include <hip/hip_runtime.h>

#define HD 1024
#define ID 1024
#define BATCH 64
#define SEQ 512
#define BS (BATCH*SEQ)     // 32768 rows
#define CHUNK 64
#define NCHUNK (SEQ/CHUNK) // 8
#define LR_OVER_I (0.01f/1024.0f)

typedef unsigned int u32;
typedef unsigned short ushort_t;
typedef __attribute__((ext_vector_type(8))) short short8;        // 8 bf16 (4 VGPRs)
typedef __attribute__((ext_vector_type(8))) unsigned short ushort8;
typedef __attribute__((ext_vector_type(4))) unsigned short ushort4v;
typedef __attribute__((ext_vector_type(4))) float floatx4;

__device__ inline ushort_t f2bf(float f) {
    union { float f; u32 u; } v; v.f = f;
    return (ushort_t)((v.u + 0x7FFFu + ((v.u >> 16) & 1u)) >> 16);  // RNE
}
__device__ inline float bf2f(ushort_t h) {
    union { u32 u; float f; } v; v.u = ((u32)h) << 16; return v.f;
}

__device__ inline void load_lds16(const void* g, void* l) {
    __builtin_amdgcn_global_load_lds(
        (const __attribute__((address_space(1))) u32*)g,
        (__attribute__((address_space(3))) u32*)l, 16, 0, 0);
}

// ---------- bd = b_init - bt ----------
__global__ void prep_b(const float* __restrict__ bi, const float* __restrict__ bt,
                       float* __restrict__ bd)
{
    int i = blockIdx.x * 256 + threadIdx.x;
    if (i < ID) bd[i] = bi[i] - bt[i];
}

// ---------- WdT = bf16((Wi - Wt)^T), WtT = bf16(Wt^T) ----------
__global__ void prep_w(const float* __restrict__ Wi, const float* __restrict__ Wt,
                       ushort_t* __restrict__ WdT, ushort_t* __restrict__ WtT)
{
    __shared__ float ti[32][33], tt[32][33];
    int r0 = blockIdx.y * 32, c0 = blockIdx.x * 32;
    for (int i = threadIdx.y; i < 32; i += 8) {
        ti[i][threadIdx.x] = Wi[(long)(r0 + i) * ID + c0 + threadIdx.x];
        tt[i][threadIdx.x] = Wt[(long)(r0 + i) * ID + c0 + threadIdx.x];
    }
    __syncthreads();
    for (int i = threadIdx.y; i < 32; i += 8) {
        float wi = ti[threadIdx.x][i];
        float wt = tt[threadIdx.x][i];
        WdT[(long)(c0 + i) * HD + r0 + threadIdx.x] = f2bf(wi - wt);
        WtT[(long)(c0 + i) * HD + r0 + threadIdx.x] = f2bf(wt);
    }
}

// ---------- out[c][r] (row stride ldo) = bf16(in[r][c]) ----------
__global__ void transpose_bf16(const float* __restrict__ in, ushort_t* __restrict__ out,
                               int C, int ldo)
{
    __shared__ float t[32][33];
    int r0 = blockIdx.y * 32, c0 = blockIdx.x * 32;
    for (int i = threadIdx.y; i < 32; i += 8)
        t[i][threadIdx.x] = in[(long)(r0 + i) * C + c0 + threadIdx.x];
    __syncthreads();
    for (int i = threadIdx.y; i < 32; i += 8)
        out[(long)(c0 + i) * ldo + r0 + threadIdx.x] = f2bf(t[threadIdx.x][i]);
}

// ---------- fp32 -> bf16 ----------
__global__ void convert_bf16(const float* __restrict__ in, ushort_t* __restrict__ out)
{
    long i = ((long)blockIdx.x * 256 + threadIdx.x) * 8;
    float4 a = *(const float4*)(in + i);
    float4 b = *(const float4*)(in + i + 4);
    ushort8 o;
    o[0] = f2bf(a.x); o[1] = f2bf(a.y); o[2] = f2bf(a.z); o[3] = f2bf(a.w);
    o[4] = f2bf(b.x); o[5] = f2bf(b.y); o[6] = f2bf(b.z); o[7] = f2bf(b.w);
    *(ushort8*)(out + i) = o;
}

// ---------- bf16 MFMA GEMM: C = alpha*(A @ Bt^T) + add0 + bias [+ C] ----------
// A = [A0 | A1] two optional K-segments (each KSEG wide), bf16 row-major.
// Bt [N, Ktot] bf16 row-major. C fp32 or bf16 (flags&1).
// flags&2: skip tiles N0>M0. flags&4: accumulate into f32 C (RMW).
// flags&8: M-valid = 64 — waves with wm==64 compute staged garbage (valid mem) and skip stores.
// 128x128 tile, BK=32, 4 waves each 64x64 via 4x4 mfma_f32_16x16x32_bf16.
// XCD-swizzle: M-tile pinned to xcd = L&7 so each A-tile is fetched by ONE XCD.
__global__ __launch_bounds__(256, 3) void gemm_bf16(
    const ushort_t* __restrict__ A0, long sA0, int lda0,
    const ushort_t* __restrict__ A1, long sA1, int lda1,
    const ushort_t* __restrict__ Bt, long sBb, int ldb,
    void* __restrict__ Cv, long sCb, int ldc,
    int KSEG, const float* __restrict__ bias,
    float alpha, float add0, int flags)
{
    int bx, by;
    {
        int L = blockIdx.y * gridDim.x + blockIdx.x;
        if ((gridDim.y & 7) == 0) {
            int xcd = L & 7, g = L >> 3;
            bx = g % gridDim.x;
            by = (g / gridDim.x) * 8 + xcd;
        } else { bx = blockIdx.x; by = blockIdx.y; }
    }
    const int M0 = by * 128, N0 = bx * 128;
    if ((flags & 2) && N0 > M0) return;

    __shared__ ushort_t As[128 * 32];
    __shared__ ushort_t Bs[128 * 32];
    const int tid = threadIdx.x;
    const int wave = tid >> 6, lane = tid & 63;
    const int lr = lane & 15, lq = lane >> 4;
    const int wm = (wave & 1) * 64, wn = (wave >> 1) * 64;

    ushort_t* la0 = &As[(wave * 16)      * 32];
    ushort_t* la1 = &As[(wave * 16 + 64) * 32];
    ushort_t* lb0 = &Bs[(wave * 16)      * 32];
    ushort_t* lb1 = &Bs[(wave * 16 + 64) * 32];

    // B staging pointer runs over the FULL K (both segments contiguous in Bt)
    const ushort_t* gb0 = Bt + (long)blockIdx.z * sBb
                        + (long)(N0 + wave * 16 + (lane >> 2)) * ldb + (lane & 3) * 8;
    const ushort_t* gb1 = gb0 + 64L * ldb;

    floatx4 acc[4][4] = {};

    for (int seg = 0; seg < 2; ++seg) {
        const ushort_t* Ag = (seg == 0) ? A0 : A1;
        if (!Ag) break;
        const int lda = (seg == 0) ? lda0 : lda1;
        Ag += (long)blockIdx.z * ((seg == 0) ? sA0 : sA1);
        const ushort_t* ga0 = Ag + (long)(M0 + wave * 16 + (lane >> 2)) * lda + (lane & 3) * 8;
        const ushort_t* ga1 = ga0 + 64L * lda;

        for (int k0 = 0; k0 < KSEG; k0 += 32) {
            load_lds16(ga0, la0);
            load_lds16(ga1, la1);
            load_lds16(gb0, lb0);
            load_lds16(gb1, lb1);
            ga0 += 32; ga1 += 32; gb0 += 32; gb1 += 32;
            __syncthreads();
            short8 af[4], bf4[4];
#pragma unroll
            for (int i = 0; i < 4; ++i)
                af[i] = *(const short8*)&As[(wm + i * 16 + lr) * 32 + lq * 8];
#pragma unroll
            for (int j = 0; j < 4; ++j)
                bf4[j] = *(const short8*)&Bs[(wn + j * 16 + lr) * 32 + lq * 8];
#pragma unroll
            for (int i = 0; i < 4; ++i)
#pragma unroll
                for (int j = 0; j < 4; ++j)
                    acc[i][j] = __builtin_amdgcn_mfma_f32_16x16x32_bf16(
                        af[i], bf4[j], acc[i][j], 0, 0, 0);
            __syncthreads();
        }
    }

    // C/D layout: col = lane&15, row = (lane>>4)*4 + reg
    float bv[4] = {0.f, 0.f, 0.f, 0.f};
    if (bias) {
#pragma unroll
        for (int j = 0; j < 4; ++j) bv[j] = bias[N0 + wn + j * 16 + lr];
    }
    if (flags & 1) {
        ushort_t* C = (ushort_t*)Cv + (long)blockIdx.z * sCb;
#pragma unroll
        for (int i = 0; i < 4; ++i)
#pragma unroll
            for (int r = 0; r < 4; ++r) {
                int row = M0 + wm + i * 16 + lq * 4 + r;
                ushort_t* cp = C + (long)row * ldc + N0 + wn + lr;
#pragma unroll
                for (int j = 0; j < 4; ++j)
                    cp[j * 16] = f2bf(alpha * acc[i][j][r] + add0 + bv[j]);
            }
    } else {
        if ((flags & 8) && wm) return;   // M-valid=64: upper waves store nothing
        float* C = (float*)Cv + (long)blockIdx.z * sCb;
#pragma unroll
        for (int i = 0; i < 4; ++i)
#pragma unroll
            for (int r = 0; r < 4; ++r) {
                int row = M0 + wm + i * 16 + lq * 4 + r;
                float* cp = C + (long)row * ldc + N0 + wn + lr;
#pragma unroll
                for (int j = 0; j < 4; ++j) {
                    float val = alpha * acc[i][j][r] + add0 + bv[j];
                    if (flags & 4) val += cp[j * 16];
                    cp[j * 16] = val;
                }
            }
    }
}

// ---------- intra-chunk unit-lower-triangular solve (64 steps, unrolled) ----------
// gram is bf16 now; G block staged to LDS once (broadcast reads in recurrence).
// Also emits EbT[i][s] = bf16(E[s][i]) for the solved chunk — the transposed
// operand the inter-chunk MFMA update needs as Bt.
__global__ __launch_bounds__(256) void intra_solve(float* __restrict__ err,
                                                   const ushort_t* __restrict__ gram,
                                                   ushort_t* __restrict__ ebt, int c)
{
    const int b = blockIdx.x >> 2;
    const int j = ((blockIdx.x & 3) << 8) + threadIdx.x;
    const int t0 = c << 6;
    float* E = err + (long)b * SEQ * ID + (long)t0 * ID + j;
    const ushort_t* Gp = gram + (long)b * SEQ * SEQ + (long)t0 * SEQ + t0;
    __shared__ float Gs[64][64];
    for (int v = threadIdx.x; v < 512; v += 256) {
        int row = v >> 3, col8 = (v & 7) << 3;
        ushort8 g8 = *(const ushort8*)(Gp + (long)row * SEQ + col8);
#pragma unroll
        for (int k = 0; k < 8; ++k) Gs[row][col8 + k] = bf2f(g8[k]);
    }
    __syncthreads();
    float e[64];
    e[0] = E[0];
#pragma unroll
    for (int t = 1; t < 64; ++t) {
        float v = E[(long)t * ID];
        float p0 = 0.f, p1 = 0.f, p2 = 0.f, p3 = 0.f;   // 4-way ILP on the chain
#pragma unroll
        for (int s = 0; s + 3 < t; s += 4) {
            p0 = fmaf(Gs[t][s + 0], e[s + 0], p0);
            p1 = fmaf(Gs[t][s + 1], e[s + 1], p1);
            p2 = fmaf(Gs[t][s + 2], e[s + 2], p2);
            p3 = fmaf(Gs[t][s + 3], e[s + 3], p3);
        }
#pragma unroll
        for (int s = t & ~3; s < t; ++s)
            p0 = fmaf(Gs[t][s], e[s], p0);
        float r = v - ((p0 + p1) + (p2 + p3));
        e[t] = r;
        E[(long)t * ID] = r;
    }
    // transposed bf16 copy of the solved chunk: EbT row j, cols t0..t0+63
    ushort_t* EB = ebt + (long)b * ID * SEQ + (long)j * SEQ + t0;
#pragma unroll
    for (int g = 0; g < 8; ++g) {
        ushort8 o;
#pragma unroll
        for (int k = 0; k < 8; ++k) o[k] = f2bf(e[g * 8 + k]);
        *(ushort8*)(EB + g * 8) = o;
    }
}

// ---------- hb = bf16(silu(err + target)), target in bf16 ----------
__global__ void silu_kernel(const float* __restrict__ err, const ushort_t* __restrict__ tgtb,
                            ushort_t* __restrict__ hb)
{
    long i = ((long)blockIdx.x * 256 + threadIdx.x) * 8;
    float4 e0 = *(const float4*)(err + i);
    float4 e1 = *(const float4*)(err + i + 4);
    ushort8 t8 = *(const ushort8*)(tgtb + i);
    float in[8] = {e0.x + bf2f(t8[0]), e0.y + bf2f(t8[1]),
                   e0.z + bf2f(t8[2]), e0.w + bf2f(t8[3]),
                   e1.x + bf2f(t8[4]), e1.y + bf2f(t8[5]),
                   e1.z + bf2f(t8[6]), e1.w + bf2f(t8[7])};
    ushort8 o;
#pragma unroll
    for (int k = 0; k < 8; ++k) {
        float v = in[k];
        o[k] = f2bf(v / (1.0f + __expf(-v)));
    }
    *(ushort8*)(hb + i) = o;
}

// ---------- gate + residual mix + LayerNorm (z, ttt in bf16) ----------
__global__ __launch_bounds__(256) void gate_ln(
    const ushort_t* __restrict__ zb, const ushort_t* __restrict__ tttb,
    const float* __restrict__ x, const float* __restrict__ gamma,
    const float* __restrict__ bet, float* __restrict__ out)
{
    long base = (long)blockIdx.x * HD + threadIdx.x * 4;
    ushort4v zv4 = *(const ushort4v*)(zb + base);
    ushort4v tv4 = *(const ushort4v*)(tttb + base);
    float4 xv = *(const float4*)(x + base);
    float xr[4] = {xv.x, xv.y, xv.z, xv.w};
    float y[4];
#pragma unroll
    for (int k = 0; k < 4; ++k) {
        float g = 1.0f / (1.0f + __expf(-bf2f(zv4[k])));
        float t = bf2f(tv4[k]);
        y[k] = g * t + (1.0f - g) * xr[k];
    }
    float sum = y[0] + y[1] + y[2] + y[3];
    float sq  = y[0]*y[0] + y[1]*y[1] + y[2]*y[2] + y[3]*y[3];
#pragma unroll
    for (int off = 32; off > 0; off >>= 1) {
        sum += __shfl_down(sum, off);
        sq  += __shfl_down(sq, off);
    }
    __shared__ float s1[4], s2[4];
    int wid = threadIdx.x >> 6;
    if ((threadIdx.x & 63) == 0) { s1[wid] = sum; s2[wid] = sq; }
    __syncthreads();
    float tot = s1[0] + s1[1] + s1[2] + s1[3];
    float tsq = s2[0] + s2[1] + s2[2] + s2[3];
    float mu = tot * (1.0f / HD);
    float var = tsq * (1.0f / HD) - mu * mu;
    float rs = rsqrtf(var + 1e-5f);
    int col = threadIdx.x * 4;
    float4 ov;
    ov.x = (y[0] - mu) * rs * gamma[col + 0] + bet[col + 0];
    ov.y = (y[1] - mu) * rs * gamma[col + 1] + bet[col + 1];
    ov.z = (y[2] - mu) * rs * gamma[col + 2] + bet[col + 2];
    ov.w = (y[3] - mu) * rs * gamma[col + 3] + bet[col + 3];
    *(float4*)(out + base) = ov;
}

extern "C" void kernel_launch(void* const* d_in, const int* in_sizes, int n_in,
                              void* d_out, int out_size, void* d_ws, size_t ws_size,
                              hipStream_t stream)
{
    const float* x    = (const float*)d_in[0];
    const float* Wi   = (const float*)d_in[1];
    const float* bi   = (const float*)d_in[2];
    const float* Wt   = (const float*)d_in[3];
    const float* bt   = (const float*)d_in[4];
    const float* Wo   = (const float*)d_in[5];
    const float* bo   = (const float*)d_in[6];
    const float* Wg   = (const float*)d_in[7];
    const float* bg   = (const float*)d_in[8];
    const float* gam  = (const float*)d_in[9];
    const float* bet  = (const float*)d_in[10];
    float* out = (float*)d_out;

    // Workspace ~394 MB (unchanged footprint):
    //   u    [BS,ID] f32 128MB : RHS/err through solve; AFTER silu reused as zb bf16
    //   tgtb [BS,ID] bf16 64MB : target (bf16)
    //   gram region       64MB : gramb bf16 [B,S,S] (32MB) in first half; AFTER solve hb bf16 overlays
    //   xb   [BS,HD] bf16 64MB : x bf16 (live until z GEMM)
    //   tttb [BS,HD] bf16 64MB : DURING solve overlaid by EbT bf16 [B,ID,SEQ]; after: ttt
    //   weights bf16 ~10MB + bd
    float* u       = (float*)d_ws;
    ushort_t* tgtb = (ushort_t*)(u + (long)BS * ID);
    float* gram    = (float*)(tgtb + (long)BS * ID);
    ushort_t* xb   = (ushort_t*)(gram + (long)BATCH * SEQ * SEQ);
    ushort_t* tttb = xb + (long)BS * HD;
    ushort_t* WdT  = tttb + (long)BS * HD;            // [ID,HD]
    ushort_t* WtT  = WdT + (long)HD * ID;             // [ID,HD]
    ushort_t* WoT  = WtT + (long)HD * ID;             // [HD,ID]
    ushort_t* WgT  = WoT + (long)HD * ID;             // [HD, 2*HD] concat K
    float* bd      = (float*)(WgT + (long)HD * 2 * HD);
    ushort_t* gramb = (ushort_t*)gram;                // gram stored bf16 (32MB of 64MB region)
    ushort_t* ebt   = (ushort_t*)tttb;                // overlay: EbT during solve
    ushort_t* hb    = (ushort_t*)gram;                // overlay: after solve
    ushort_t* zb    = (ushort_t*)u;                   // overlay: after silu

    // ---- prep ----
    prep_b<<<4, 256, 0, stream>>>(bi, bt, bd);
    prep_w<<<dim3(32, 32), dim3(32, 8), 0, stream>>>(Wi, Wt, WdT, WtT);
    transpose_bf16<<<dim3(32, 32), dim3(32, 8), 0, stream>>>(Wo, WoT, HD, ID);
    transpose_bf16<<<dim3(32, 32), dim3(32, 8), 0, stream>>>(Wg, WgT, HD, 2 * HD);
    transpose_bf16<<<dim3(32, 32), dim3(32, 8), 0, stream>>>(Wg + (long)HD * HD, WgT + HD, HD, 2 * HD);
    convert_bf16<<<16384, 256, 0, stream>>>(x, xb);

    dim3 gBig(ID / 128, BS / 128, 1);   // 8 x 256
    // u = x @ (Wi - Wt) + (bi - bt)   [f32 out]
    gemm_bf16<<<gBig, 256, 0, stream>>>(xb, 0, HD, nullptr, 0, 0, WdT, 0, HD,
                                        u, 0, ID, HD, bd, 1.f, 0.f, 0);
    // target = x @ Wt + bt            [bf16 out]
    gemm_bf16<<<gBig, 256, 0, stream>>>(xb, 0, HD, nullptr, 0, 0, WtT, 0, HD,
                                        tgtb, 0, ID, HD, bt, 1.f, 0.f, 1);
    // gram = (LR/I) * (X X^T + 1)     [bf16 out, lower tiles only]
    gemm_bf16<<<dim3(SEQ / 128, SEQ / 128, BATCH), 256, 0, stream>>>(
        xb, (long)SEQ * HD, HD, nullptr, 0, 0, xb, (long)SEQ * HD, HD,
        gramb, (long)SEQ * SEQ, SEQ, HD, nullptr, LR_OVER_I, LR_OVER_I, 2 | 1);

    // ---- blocked forward substitution: err = (I + A_strict)^-1 u ----
    // inter-chunk update on MFMA: E_c -= G[c-rows, 0:K] @ E_prev, via
    // A = gramb chunk rows [64,K] bf16, Bt = EbT [1024,K] bf16, C = u (f32 RMW).
    for (int c = 0; c < NCHUNK; ++c) {
        if (c > 0) {
            gemm_bf16<<<dim3(ID / 128, 1, BATCH), 256, 0, stream>>>(
                gramb + (long)c * CHUNK * SEQ, (long)SEQ * SEQ, SEQ,
                nullptr, 0, 0,
                ebt, (long)ID * SEQ, SEQ,
                u + (long)c * CHUNK * ID, (long)SEQ * ID, ID,
                c * CHUNK, nullptr, -1.f, 0.f, 4 | 8);
        }
        intra_solve<<<BATCH * 4, 256, 0, stream>>>(u, gramb, ebt, c);
    }

    // hb = bf16(silu(err + target))   (hb overlays gram)
    silu_kernel<<<16384, 256, 0, stream>>>(u, tgtb, hb);
    // ttt = h @ Wo + bo               [bf16 out]
    gemm_bf16<<<gBig, 256, 0, stream>>>(hb, 0, ID, nullptr, 0, 0, WoT, 0, ID,
                                        tttb, 0, HD, ID, bo, 1.f, 0.f, 1);
    // z = [x, ttt] @ Wg + bg          [bf16 out, two K-segments; zb overlays u]
    gemm_bf16<<<gBig, 256, 0, stream>>>(xb, 0, HD, tttb, 0, HD, WgT, 0, 2 * HD,
                                        zb, 0, HD, HD, bg, 1.f, 0.f, 1);
    // out = LN(g*ttt + (1-g)*x)
    gate_ln<<<BS, 256, 0, stream>>>(zb, tttb, x, gam, bet, out);
}

// Round 2
// 1092.822 us; speedup vs baseline: 1.2791x; 1.1357x over previous
//
#include <hip/hip_runtime.h>

#define HD 1024
#define ID 1024
#define BATCH 64
#define SEQ 512
#define BS (BATCH*SEQ)     // 32768 rows
#define CHUNK 64
#define NCHUNK (SEQ/CHUNK) // 8
#define LR_OVER_I (0.01f/1024.0f)

typedef unsigned int u32;
typedef unsigned short ushort_t;
typedef __attribute__((ext_vector_type(8))) short short8;        // 8 bf16 (4 VGPRs)
typedef __attribute__((ext_vector_type(8))) unsigned short ushort8;
typedef __attribute__((ext_vector_type(4))) unsigned short ushort4v;
typedef __attribute__((ext_vector_type(4))) float floatx4;

__device__ inline ushort_t f2bf(float f) {
    union { float f; u32 u; } v; v.f = f;
    return (ushort_t)((v.u + 0x7FFFu + ((v.u >> 16) & 1u)) >> 16);  // RNE
}
__device__ inline float bf2f(ushort_t h) {
    union { u32 u; float f; } v; v.u = ((u32)h) << 16; return v.f;
}

__device__ inline void load_lds16(const void* g, void* l) {
    __builtin_amdgcn_global_load_lds(
        (const __attribute__((address_space(1))) u32*)g,
        (__attribute__((address_space(3))) u32*)l, 16, 0, 0);
}

// ---------- WdT = bf16((Wi - Wt)^T), WtT = bf16(Wt^T); also bd = bi - bt ----------
__global__ void prep_w(const float* __restrict__ Wi, const float* __restrict__ Wt,
                       ushort_t* __restrict__ WdT, ushort_t* __restrict__ WtT,
                       const float* __restrict__ bi, const float* __restrict__ bt,
                       float* __restrict__ bd)
{
    if (blockIdx.x == 0 && blockIdx.y == 0) {
        int t = threadIdx.y * 32 + threadIdx.x;
        for (int i = t; i < ID; i += 256) bd[i] = bi[i] - bt[i];
    }
    __shared__ float ti[32][33], tt[32][33];
    int r0 = blockIdx.y * 32, c0 = blockIdx.x * 32;
    for (int i = threadIdx.y; i < 32; i += 8) {
        ti[i][threadIdx.x] = Wi[(long)(r0 + i) * ID + c0 + threadIdx.x];
        tt[i][threadIdx.x] = Wt[(long)(r0 + i) * ID + c0 + threadIdx.x];
    }
    __syncthreads();
    for (int i = threadIdx.y; i < 32; i += 8) {
        float wi = ti[threadIdx.x][i];
        float wt = tt[threadIdx.x][i];
        WdT[(long)(c0 + i) * HD + r0 + threadIdx.x] = f2bf(wi - wt);
        WtT[(long)(c0 + i) * HD + r0 + threadIdx.x] = f2bf(wt);
    }
}

// ---------- 3 weight transposes in one launch (z selects) ----------
__global__ void prep_transposes(const float* __restrict__ Wo, const float* __restrict__ Wg,
                                ushort_t* __restrict__ WoT, ushort_t* __restrict__ WgT)
{
    const float* in; ushort_t* out; int ldo;
    if (blockIdx.z == 0)      { in = Wo;                   out = WoT;      ldo = ID; }
    else if (blockIdx.z == 1) { in = Wg;                   out = WgT;      ldo = 2 * HD; }
    else                      { in = Wg + (long)HD * HD;   out = WgT + HD; ldo = 2 * HD; }
    __shared__ float t[32][33];
    int r0 = blockIdx.y * 32, c0 = blockIdx.x * 32;
    for (int i = threadIdx.y; i < 32; i += 8)
        t[i][threadIdx.x] = in[(long)(r0 + i) * HD + c0 + threadIdx.x];
    __syncthreads();
    for (int i = threadIdx.y; i < 32; i += 8)
        out[(long)(c0 + i) * ldo + r0 + threadIdx.x] = f2bf(t[threadIdx.x][i]);
}

// ---------- fp32 -> bf16 ----------
__global__ void convert_bf16(const float* __restrict__ in, ushort_t* __restrict__ out)
{
    long i = ((long)blockIdx.x * 256 + threadIdx.x) * 8;
    float4 a = *(const float4*)(in + i);
    float4 b = *(const float4*)(in + i + 4);
    ushort8 o;
    o[0] = f2bf(a.x); o[1] = f2bf(a.y); o[2] = f2bf(a.z); o[3] = f2bf(a.w);
    o[4] = f2bf(b.x); o[5] = f2bf(b.y); o[6] = f2bf(b.z); o[7] = f2bf(b.w);
    *(ushort8*)(out + i) = o;
}

// ---------- bf16 MFMA GEMM: C = alpha*(A @ Bt^T) + add0 + bias [+ C] ----------
// A = [A0 | A1] two optional K-segments (each KSEG wide), bf16 row-major.
// Bt [N, Ktot] bf16 row-major. C fp32 or bf16 (fl&1).
// fl&2: skip tiles N0>M0. fl&4: accumulate into f32 C (RMW).
// fl&8: M-valid = 64 (upper waves skip stores).
// flags&16: DUAL mode — blockIdx.z==1 selects {Bt2, Cv2, bias2, flags2}; z-batch offsets = 0.
// 128x128 tile, BK=32, 4 waves each 64x64 via 4x4 mfma_f32_16x16x32_bf16.
__global__ __launch_bounds__(256, 3) void gemm_bf16(
    const ushort_t* __restrict__ A0, long sA0, int lda0,
    const ushort_t* __restrict__ A1, long sA1, int lda1,
    const ushort_t* __restrict__ Bt, long sBb, int ldb,
    void* __restrict__ Cv, long sCb, int ldc,
    int KSEG, const float* __restrict__ bias,
    float alpha, float add0, int flags,
    const ushort_t* __restrict__ Bt2, void* __restrict__ Cv2,
    const float* __restrict__ bias2, int flags2)
{
    long zb = blockIdx.z;
    int fl = flags;
    if (flags & 16) {
        zb = 0;
        if (blockIdx.z == 1) { Bt = Bt2; Cv = Cv2; bias = bias2; fl = flags2; }
    }
    int bx, by;
    {
        int L = blockIdx.y * gridDim.x + blockIdx.x;
        if ((gridDim.y & 7) == 0) {
            int xcd = L & 7, g = L >> 3;
            bx = g % gridDim.x;
            by = (g / gridDim.x) * 8 + xcd;
        } else { bx = blockIdx.x; by = blockIdx.y; }
    }
    const int M0 = by * 128, N0 = bx * 128;
    if ((fl & 2) && N0 > M0) return;

    __shared__ ushort_t As[128 * 32];
    __shared__ ushort_t Bs[128 * 32];
    const int tid = threadIdx.x;
    const int wave = tid >> 6, lane = tid & 63;
    const int lr = lane & 15, lq = lane >> 4;
    const int wm = (wave & 1) * 64, wn = (wave >> 1) * 64;

    ushort_t* la0 = &As[(wave * 16)      * 32];
    ushort_t* la1 = &As[(wave * 16 + 64) * 32];
    ushort_t* lb0 = &Bs[(wave * 16)      * 32];
    ushort_t* lb1 = &Bs[(wave * 16 + 64) * 32];

    const ushort_t* gb0 = Bt + zb * sBb
                        + (long)(N0 + wave * 16 + (lane >> 2)) * ldb + (lane & 3) * 8;
    const ushort_t* gb1 = gb0 + 64L * ldb;

    floatx4 acc[4][4] = {};

    for (int seg = 0; seg < 2; ++seg) {
        const ushort_t* Ag = (seg == 0) ? A0 : A1;
        if (!Ag) break;
        const int lda = (seg == 0) ? lda0 : lda1;
        Ag += zb * ((seg == 0) ? sA0 : sA1);
        const ushort_t* ga0 = Ag + (long)(M0 + wave * 16 + (lane >> 2)) * lda + (lane & 3) * 8;
        const ushort_t* ga1 = ga0 + 64L * lda;

        for (int k0 = 0; k0 < KSEG; k0 += 32) {
            load_lds16(ga0, la0);
            load_lds16(ga1, la1);
            load_lds16(gb0, lb0);
            load_lds16(gb1, lb1);
            ga0 += 32; ga1 += 32; gb0 += 32; gb1 += 32;
            __syncthreads();
            short8 af[4], bf4[4];
#pragma unroll
            for (int i = 0; i < 4; ++i)
                af[i] = *(const short8*)&As[(wm + i * 16 + lr) * 32 + lq * 8];
#pragma unroll
            for (int j = 0; j < 4; ++j)
                bf4[j] = *(const short8*)&Bs[(wn + j * 16 + lr) * 32 + lq * 8];
#pragma unroll
            for (int i = 0; i < 4; ++i)
#pragma unroll
                for (int j = 0; j < 4; ++j)
                    acc[i][j] = __builtin_amdgcn_mfma_f32_16x16x32_bf16(
                        af[i], bf4[j], acc[i][j], 0, 0, 0);
            __syncthreads();
        }
    }

    // C/D layout: col = lane&15, row = (lane>>4)*4 + reg
    float bv[4] = {0.f, 0.f, 0.f, 0.f};
    if (bias) {
#pragma unroll
        for (int j = 0; j < 4; ++j) bv[j] = bias[N0 + wn + j * 16 + lr];
    }
    if (fl & 1) {
        ushort_t* C = (ushort_t*)Cv + zb * sCb;
#pragma unroll
        for (int i = 0; i < 4; ++i)
#pragma unroll
            for (int r = 0; r < 4; ++r) {
                int row = M0 + wm + i * 16 + lq * 4 + r;
                ushort_t* cp = C + (long)row * ldc + N0 + wn + lr;
#pragma unroll
                for (int j = 0; j < 4; ++j)
                    cp[j * 16] = f2bf(alpha * acc[i][j][r] + add0 + bv[j]);
            }
    } else {
        if ((fl & 8) && wm) return;
        float* C = (float*)Cv + zb * sCb;
#pragma unroll
        for (int i = 0; i < 4; ++i)
#pragma unroll
            for (int r = 0; r < 4; ++r) {
                int row = M0 + wm + i * 16 + lq * 4 + r;
                float* cp = C + (long)row * ldc + N0 + wn + lr;
#pragma unroll
                for (int j = 0; j < 4; ++j) {
                    float val = alpha * acc[i][j][r] + add0 + bv[j];
                    if (fl & 4) val += cp[j * 16];
                    cp[j * 16] = val;
                }
            }
    }
}

// ---------- fused per-chunk solve: [inter-chunk MFMA update] + intra solve ----------
// Grid (4, 1, BATCH), 256 threads. Block owns a 64x256 slab of one batch:
//   phase 1 (c>0): E_c -= G[chunk rows, 0:K] @ E_prev  (A=gram bf16, B=EbT bf16, RMW u)
//   phase 2: unit-lower-triangular solve down the 64 rows (register recurrence)
//   phase 3: emit EbT (transposed bf16) for later chunks
__global__ __launch_bounds__(256) void solve_chunk(float* __restrict__ u,
                                                   const ushort_t* __restrict__ gram,
                                                   ushort_t* __restrict__ ebt, int c)
{
    const int b = blockIdx.z;
    const int j0 = blockIdx.x << 8;          // 0,256,512,768
    const int t0 = c << 6;
    const int tid = threadIdx.x;
    const int wave = tid >> 6, lane = tid & 63;
    const int lr = lane & 15, lq = lane >> 4;

    __shared__ __align__(16) char smem[4096 + 16384];   // As 4KB | Bs 16KB ; reused as Gs 16KB
    ushort_t* As = (ushort_t*)smem;
    ushort_t* Bs = (ushort_t*)(smem + 4096);
    float* Gs = (float*)smem;

    const ushort_t* Gb = gram + (long)b * SEQ * SEQ + (long)t0 * SEQ;   // 64 x SEQ chunk rows
    float* Ub = u + (long)b * SEQ * ID + (long)t0 * ID;                 // 64 x ID chunk slab
    ushort_t* Eb = ebt + (long)b * ID * SEQ;                            // ID x SEQ transposed E

    if (c > 0) {
        const int K = c << 6;
        floatx4 acc[4][4] = {};
        const ushort_t* ga = Gb + (long)(wave * 16 + (lane >> 2)) * SEQ + (lane & 3) * 8;
        const ushort_t* gb = Eb + (long)(j0 + wave * 16 + (lane >> 2)) * SEQ + (lane & 3) * 8;
        ushort_t* la  = &As[(wave * 16) * 32];
        ushort_t* lb0 = &Bs[(wave * 16)       * 32];
        ushort_t* lb1 = &Bs[(64  + wave * 16) * 32];
        ushort_t* lb2 = &Bs[(128 + wave * 16) * 32];
        ushort_t* lb3 = &Bs[(192 + wave * 16) * 32];
        for (int k0 = 0; k0 < K; k0 += 32) {
            load_lds16(ga, la);
            load_lds16(gb,             lb0);
            load_lds16(gb + 64L * SEQ, lb1);
            load_lds16(gb + 128L * SEQ, lb2);
            load_lds16(gb + 192L * SEQ, lb3);
            ga += 32; gb += 32;
            __syncthreads();
            short8 af[4], bf4[4];
#pragma unroll
            for (int i = 0; i < 4; ++i)
                af[i] = *(const short8*)&As[(i * 16 + lr) * 32 + lq * 8];
#pragma unroll
            for (int j = 0; j < 4; ++j)
                bf4[j] = *(const short8*)&Bs[(wave * 64 + j * 16 + lr) * 32 + lq * 8];
#pragma unroll
            for (int i = 0; i < 4; ++i)
#pragma unroll
                for (int j = 0; j < 4; ++j)
                    acc[i][j] = __builtin_amdgcn_mfma_f32_16x16x32_bf16(
                        af[i], bf4[j], acc[i][j], 0, 0, 0);
            __syncthreads();
        }
        // subtract: u[row][col] -= acc   (C/D layout: col=lane&15, row=lq*4+reg)
#pragma unroll
        for (int i = 0; i < 4; ++i)
#pragma unroll
            for (int r = 0; r < 4; ++r) {
                int row = i * 16 + lq * 4 + r;
                float* up = Ub + (long)row * ID + j0 + wave * 64 + lr;
#pragma unroll
                for (int j = 0; j < 4; ++j)
                    up[j * 16] -= acc[i][j][r];
            }
        __syncthreads();   // drain stores; block-level visibility (same CU/L1)
    }

    // stage G diag block (bf16 -> f32 LDS)
    for (int v = tid; v < 512; v += 256) {
        int row = v >> 3, col8 = (v & 7) << 3;
        ushort8 g8 = *(const ushort8*)(Gb + (long)row * SEQ + t0 + col8);
#pragma unroll
        for (int k = 0; k < 8; ++k) Gs[row * 64 + col8 + k] = bf2f(g8[k]);
    }
    __syncthreads();

    // intra-chunk forward substitution, one column per thread
    const int j = j0 + tid;
    float* E = Ub + j;
    float e[64];
    e[0] = E[0];
#pragma unroll
    for (int t = 1; t < 64; ++t) {
        float v = E[(long)t * ID];
        float p0 = 0.f, p1 = 0.f, p2 = 0.f, p3 = 0.f;   // 4-way ILP on the chain
#pragma unroll
        for (int s = 0; s + 3 < t; s += 4) {
            p0 = fmaf(Gs[t * 64 + s + 0], e[s + 0], p0);
            p1 = fmaf(Gs[t * 64 + s + 1], e[s + 1], p1);
            p2 = fmaf(Gs[t * 64 + s + 2], e[s + 2], p2);
            p3 = fmaf(Gs[t * 64 + s + 3], e[s + 3], p3);
        }
#pragma unroll
        for (int s = t & ~3; s < t; ++s)
            p0 = fmaf(Gs[t * 64 + s], e[s], p0);
        float r = v - ((p0 + p1) + (p2 + p3));
        e[t] = r;
        E[(long)t * ID] = r;
    }
    // transposed bf16 copy of the solved chunk: EbT row j, cols t0..t0+63
    ushort_t* EB = Eb + (long)j * SEQ + t0;
#pragma unroll
    for (int g = 0; g < 8; ++g) {
        ushort8 o;
#pragma unroll
        for (int k = 0; k < 8; ++k) o[k] = f2bf(e[g * 8 + k]);
        *(ushort8*)(EB + g * 8) = o;
    }
}

// ---------- hb = bf16(silu(err + target)), target in bf16 ----------
__global__ void silu_kernel(const float* __restrict__ err, const ushort_t* __restrict__ tgtb,
                            ushort_t* __restrict__ hb)
{
    long i = ((long)blockIdx.x * 256 + threadIdx.x) * 8;
    float4 e0 = *(const float4*)(err + i);
    float4 e1 = *(const float4*)(err + i + 4);
    ushort8 t8 = *(const ushort8*)(tgtb + i);
    float in[8] = {e0.x + bf2f(t8[0]), e0.y + bf2f(t8[1]),
                   e0.z + bf2f(t8[2]), e0.w + bf2f(t8[3]),
                   e1.x + bf2f(t8[4]), e1.y + bf2f(t8[5]),
                   e1.z + bf2f(t8[6]), e1.w + bf2f(t8[7])};
    ushort8 o;
#pragma unroll
    for (int k = 0; k < 8; ++k) {
        float v = in[k];
        o[k] = f2bf(v / (1.0f + __expf(-v)));
    }
    *(ushort8*)(hb + i) = o;
}

// ---------- gate + residual mix + LayerNorm (z, ttt in bf16) ----------
__global__ __launch_bounds__(256) void gate_ln(
    const ushort_t* __restrict__ zb, const ushort_t* __restrict__ tttb,
    const float* __restrict__ x, const float* __restrict__ gamma,
    const float* __restrict__ bet, float* __restrict__ out)
{
    long base = (long)blockIdx.x * HD + threadIdx.x * 4;
    ushort4v zv4 = *(const ushort4v*)(zb + base);
    ushort4v tv4 = *(const ushort4v*)(tttb + base);
    float4 xv = *(const float4*)(x + base);
    float xr[4] = {xv.x, xv.y, xv.z, xv.w};
    float y[4];
#pragma unroll
    for (int k = 0; k < 4; ++k) {
        float g = 1.0f / (1.0f + __expf(-bf2f(zv4[k])));
        float t = bf2f(tv4[k]);
        y[k] = g * t + (1.0f - g) * xr[k];
    }
    float sum = y[0] + y[1] + y[2] + y[3];
    float sq  = y[0]*y[0] + y[1]*y[1] + y[2]*y[2] + y[3]*y[3];
#pragma unroll
    for (int off = 32; off > 0; off >>= 1) {
        sum += __shfl_down(sum, off);
        sq  += __shfl_down(sq, off);
    }
    __shared__ float s1[4], s2[4];
    int wid = threadIdx.x >> 6;
    if ((threadIdx.x & 63) == 0) { s1[wid] = sum; s2[wid] = sq; }
    __syncthreads();
    float tot = s1[0] + s1[1] + s1[2] + s1[3];
    float tsq = s2[0] + s2[1] + s2[2] + s2[3];
    float mu = tot * (1.0f / HD);
    float var = tsq * (1.0f / HD) - mu * mu;
    float rs = rsqrtf(var + 1e-5f);
    int col = threadIdx.x * 4;
    float4 ov;
    ov.x = (y[0] - mu) * rs * gamma[col + 0] + bet[col + 0];
    ov.y = (y[1] - mu) * rs * gamma[col + 1] + bet[col + 1];
    ov.z = (y[2] - mu) * rs * gamma[col + 2] + bet[col + 2];
    ov.w = (y[3] - mu) * rs * gamma[col + 3] + bet[col + 3];
    *(float4*)(out + base) = ov;
}

extern "C" void kernel_launch(void* const* d_in, const int* in_sizes, int n_in,
                              void* d_out, int out_size, void* d_ws, size_t ws_size,
                              hipStream_t stream)
{
    const float* x    = (const float*)d_in[0];
    const float* Wi   = (const float*)d_in[1];
    const float* bi   = (const float*)d_in[2];
    const float* Wt   = (const float*)d_in[3];
    const float* bt   = (const float*)d_in[4];
    const float* Wo   = (const float*)d_in[5];
    const float* bo   = (const float*)d_in[6];
    const float* Wg   = (const float*)d_in[7];
    const float* bg   = (const float*)d_in[8];
    const float* gam  = (const float*)d_in[9];
    const float* bet  = (const float*)d_in[10];
    float* out = (float*)d_out;

    // Workspace ~394 MB (unchanged footprint):
    //   u    [BS,ID] f32 128MB : RHS/err through solve; AFTER silu reused as zb bf16
    //   tgtb [BS,ID] bf16 64MB : target (bf16)
    //   gram region       64MB : gramb bf16 [B,S,S] (32MB); AFTER solve hb bf16 overlays
    //   xb   [BS,HD] bf16 64MB : x bf16 (live until z GEMM)
    //   tttb [BS,HD] bf16 64MB : DURING solve overlaid by EbT bf16 [B,ID,SEQ]; after: ttt
    //   weights bf16 ~10MB + bd
    float* u       = (float*)d_ws;
    ushort_t* tgtb = (ushort_t*)(u + (long)BS * ID);
    float* gram    = (float*)(tgtb + (long)BS * ID);
    ushort_t* xb   = (ushort_t*)(gram + (long)BATCH * SEQ * SEQ);
    ushort_t* tttb = xb + (long)BS * HD;
    ushort_t* WdT  = tttb + (long)BS * HD;            // [ID,HD]
    ushort_t* WtT  = WdT + (long)HD * ID;             // [ID,HD]
    ushort_t* WoT  = WtT + (long)HD * ID;             // [HD,ID]
    ushort_t* WgT  = WoT + (long)HD * ID;             // [HD, 2*HD] concat K
    float* bd      = (float*)(WgT + (long)HD * 2 * HD);
    ushort_t* gramb = (ushort_t*)gram;                // gram stored bf16
    ushort_t* ebt   = (ushort_t*)tttb;                // overlay: EbT during solve
    ushort_t* hb    = (ushort_t*)gram;                // overlay: after solve
    ushort_t* zb    = (ushort_t*)u;                   // overlay: after silu

    // ---- prep (3 launches) ----
    prep_w<<<dim3(32, 32), dim3(32, 8), 0, stream>>>(Wi, Wt, WdT, WtT, bi, bt, bd);
    prep_transposes<<<dim3(32, 32, 3), dim3(32, 8), 0, stream>>>(Wo, Wg, WoT, WgT);
    convert_bf16<<<16384, 256, 0, stream>>>(x, xb);

    dim3 gBig(ID / 128, BS / 128, 1);   // 8 x 256
    // DUAL: z=0: u = x @ (Wi - Wt) + (bi - bt) [f32]; z=1: target = x @ Wt + bt [bf16]
    gemm_bf16<<<dim3(ID / 128, BS / 128, 2), 256, 0, stream>>>(
        xb, 0, HD, nullptr, 0, 0, WdT, 0, HD,
        u, 0, ID, HD, bd, 1.f, 0.f, 16,
        WtT, tgtb, bt, 1);
    // gram = (LR/I) * (X X^T + 1)     [bf16 out, lower tiles only]
    gemm_bf16<<<dim3(SEQ / 128, SEQ / 128, BATCH), 256, 0, stream>>>(
        xb, (long)SEQ * HD, HD, nullptr, 0, 0, xb, (long)SEQ * HD, HD,
        gramb, (long)SEQ * SEQ, SEQ, HD, nullptr, LR_OVER_I, LR_OVER_I, 2 | 1,
        nullptr, nullptr, nullptr, 0);

    // ---- blocked forward substitution: err = (I + A_strict)^-1 u (8 fused launches) ----
    for (int c = 0; c < NCHUNK; ++c)
        solve_chunk<<<dim3(4, 1, BATCH), 256, 0, stream>>>(u, gramb, ebt, c);

    // hb = bf16(silu(err + target))   (hb overlays gram)
    silu_kernel<<<16384, 256, 0, stream>>>(u, tgtb, hb);
    // ttt = h @ Wo + bo               [bf16 out]
    gemm_bf16<<<gBig, 256, 0, stream>>>(hb, 0, ID, nullptr, 0, 0, WoT, 0, ID,
                                        tttb, 0, HD, ID, bo, 1.f, 0.f, 1,
                                        nullptr, nullptr, nullptr, 0);
    // z = [x, ttt] @ Wg + bg          [bf16 out, two K-segments; zb overlays u]
    gemm_bf16<<<gBig, 256, 0, stream>>>(xb, 0, HD, tttb, 0, HD, WgT, 0, 2 * HD,
                                        zb, 0, HD, HD, bg, 1.f, 0.f, 1,
                                        nullptr, nullptr, nullptr, 0);
    // out = LN(g*ttt + (1-g)*x)
    gate_ln<<<BS, 256, 0, stream>>>(zb, tttb, x, gam, bet, out);
}

// Round 3
// 1045.695 us; speedup vs baseline: 1.3367x; 1.0451x over previous
//
#include <hip/hip_runtime.h>

#define HD 1024
#define ID 1024
#define BATCH 64
#define SEQ 512
#define BS (BATCH*SEQ)     // 32768 rows
#define CHUNK 64
#define NCHUNK (SEQ/CHUNK) // 8
#define LR_OVER_I (0.01f/1024.0f)

typedef unsigned int u32;
typedef unsigned short ushort_t;
typedef __attribute__((ext_vector_type(8))) short short8;        // 8 bf16 (4 VGPRs)
typedef __attribute__((ext_vector_type(8))) unsigned short ushort8;
typedef __attribute__((ext_vector_type(4))) unsigned short ushort4v;
typedef __attribute__((ext_vector_type(4))) float floatx4;

__device__ inline ushort_t f2bf(float f) {
    union { float f; u32 u; } v; v.f = f;
    return (ushort_t)((v.u + 0x7FFFu + ((v.u >> 16) & 1u)) >> 16);  // RNE
}
__device__ inline float bf2f(ushort_t h) {
    union { u32 u; float f; } v; v.u = ((u32)h) << 16; return v.f;
}

__device__ inline void load_lds16(const void* g, void* l) {
    __builtin_amdgcn_global_load_lds(
        (const __attribute__((address_space(1))) u32*)g,
        (__attribute__((address_space(3))) u32*)l, 16, 0, 0);
}

// ---------- WdT = bf16((Wi - Wt)^T), WtT = bf16(Wt^T); also bd = bi - bt ----------
__global__ void prep_w(const float* __restrict__ Wi, const float* __restrict__ Wt,
                       ushort_t* __restrict__ WdT, ushort_t* __restrict__ WtT,
                       const float* __restrict__ bi, const float* __restrict__ bt,
                       float* __restrict__ bd)
{
    if (blockIdx.x == 0 && blockIdx.y == 0) {
        int t = threadIdx.y * 32 + threadIdx.x;
        for (int i = t; i < ID; i += 256) bd[i] = bi[i] - bt[i];
    }
    __shared__ float ti[32][33], tt[32][33];
    int r0 = blockIdx.y * 32, c0 = blockIdx.x * 32;
    for (int i = threadIdx.y; i < 32; i += 8) {
        ti[i][threadIdx.x] = Wi[(long)(r0 + i) * ID + c0 + threadIdx.x];
        tt[i][threadIdx.x] = Wt[(long)(r0 + i) * ID + c0 + threadIdx.x];
    }
    __syncthreads();
    for (int i = threadIdx.y; i < 32; i += 8) {
        float wi = ti[threadIdx.x][i];
        float wt = tt[threadIdx.x][i];
        WdT[(long)(c0 + i) * HD + r0 + threadIdx.x] = f2bf(wi - wt);
        WtT[(long)(c0 + i) * HD + r0 + threadIdx.x] = f2bf(wt);
    }
}

// ---------- 3 weight transposes in one launch (z selects) ----------
__global__ void prep_transposes(const float* __restrict__ Wo, const float* __restrict__ Wg,
                                ushort_t* __restrict__ WoT, ushort_t* __restrict__ WgT)
{
    const float* in; ushort_t* out; int ldo;
    if (blockIdx.z == 0)      { in = Wo;                   out = WoT;      ldo = ID; }
    else if (blockIdx.z == 1) { in = Wg;                   out = WgT;      ldo = 2 * HD; }
    else                      { in = Wg + (long)HD * HD;   out = WgT + HD; ldo = 2 * HD; }
    __shared__ float t[32][33];
    int r0 = blockIdx.y * 32, c0 = blockIdx.x * 32;
    for (int i = threadIdx.y; i < 32; i += 8)
        t[i][threadIdx.x] = in[(long)(r0 + i) * HD + c0 + threadIdx.x];
    __syncthreads();
    for (int i = threadIdx.y; i < 32; i += 8)
        out[(long)(c0 + i) * ldo + r0 + threadIdx.x] = f2bf(t[threadIdx.x][i]);
}

// ---------- fp32 -> bf16 ----------
__global__ void convert_bf16(const float* __restrict__ in, ushort_t* __restrict__ out)
{
    long i = ((long)blockIdx.x * 256 + threadIdx.x) * 8;
    float4 a = *(const float4*)(in + i);
    float4 b = *(const float4*)(in + i + 4);
    ushort8 o;
    o[0] = f2bf(a.x); o[1] = f2bf(a.y); o[2] = f2bf(a.z); o[3] = f2bf(a.w);
    o[4] = f2bf(b.x); o[5] = f2bf(b.y); o[6] = f2bf(b.z); o[7] = f2bf(b.w);
    *(ushort8*)(out + i) = o;
}

// ---------- bf16 MFMA GEMM: C = alpha*(A @ Bt^T) + add0 + bias [+ C] ----------
// A = [A0 | A1] two optional K-segments (each KSEG wide), bf16 row-major.
// Bt [N, Ktot] bf16 row-major. C fp32 or bf16 (fl&1).
// fl&2: skip tiles N0>M0. fl&4: accumulate into f32 C (RMW).
// fl&8: M-valid = 64 (upper waves skip stores).
// flags&16: DUAL mode — blockIdx.z==1 selects {Bt2, Cv2, bias2, flags2}; z-batch offsets = 0.
// 128x128 tile, BK=32, 4 waves each 64x64 via 4x4 mfma_f32_16x16x32_bf16.
__global__ __launch_bounds__(256, 3) void gemm_bf16(
    const ushort_t* __restrict__ A0, long sA0, int lda0,
    const ushort_t* __restrict__ A1, long sA1, int lda1,
    const ushort_t* __restrict__ Bt, long sBb, int ldb,
    void* __restrict__ Cv, long sCb, int ldc,
    int KSEG, const float* __restrict__ bias,
    float alpha, float add0, int flags,
    const ushort_t* __restrict__ Bt2, void* __restrict__ Cv2,
    const float* __restrict__ bias2, int flags2)
{
    long zb = blockIdx.z;
    int fl = flags;
    if (flags & 16) {
        zb = 0;
        if (blockIdx.z == 1) { Bt = Bt2; Cv = Cv2; bias = bias2; fl = flags2; }
    }
    int bx, by;
    {
        int L = blockIdx.y * gridDim.x + blockIdx.x;
        if ((gridDim.y & 7) == 0) {
            int xcd = L & 7, g = L >> 3;
            bx = g % gridDim.x;
            by = (g / gridDim.x) * 8 + xcd;
        } else { bx = blockIdx.x; by = blockIdx.y; }
    }
    const int M0 = by * 128, N0 = bx * 128;
    if ((fl & 2) && N0 > M0) return;

    __shared__ ushort_t As[128 * 32];
    __shared__ ushort_t Bs[128 * 32];
    const int tid = threadIdx.x;
    const int wave = tid >> 6, lane = tid & 63;
    const int lr = lane & 15, lq = lane >> 4;
    const int wm = (wave & 1) * 64, wn = (wave >> 1) * 64;

    ushort_t* la0 = &As[(wave * 16)      * 32];
    ushort_t* la1 = &As[(wave * 16 + 64) * 32];
    ushort_t* lb0 = &Bs[(wave * 16)      * 32];
    ushort_t* lb1 = &Bs[(wave * 16 + 64) * 32];

    const ushort_t* gb0 = Bt + zb * sBb
                        + (long)(N0 + wave * 16 + (lane >> 2)) * ldb + (lane & 3) * 8;
    const ushort_t* gb1 = gb0 + 64L * ldb;

    floatx4 acc[4][4] = {};

    for (int seg = 0; seg < 2; ++seg) {
        const ushort_t* Ag = (seg == 0) ? A0 : A1;
        if (!Ag) break;
        const int lda = (seg == 0) ? lda0 : lda1;
        Ag += zb * ((seg == 0) ? sA0 : sA1);
        const ushort_t* ga0 = Ag + (long)(M0 + wave * 16 + (lane >> 2)) * lda + (lane & 3) * 8;
        const ushort_t* ga1 = ga0 + 64L * lda;

        for (int k0 = 0; k0 < KSEG; k0 += 32) {
            load_lds16(ga0, la0);
            load_lds16(ga1, la1);
            load_lds16(gb0, lb0);
            load_lds16(gb1, lb1);
            ga0 += 32; ga1 += 32; gb0 += 32; gb1 += 32;
            __syncthreads();
            short8 af[4], bf4[4];
#pragma unroll
            for (int i = 0; i < 4; ++i)
                af[i] = *(const short8*)&As[(wm + i * 16 + lr) * 32 + lq * 8];
#pragma unroll
            for (int j = 0; j < 4; ++j)
                bf4[j] = *(const short8*)&Bs[(wn + j * 16 + lr) * 32 + lq * 8];
#pragma unroll
            for (int i = 0; i < 4; ++i)
#pragma unroll
                for (int j = 0; j < 4; ++j)
                    acc[i][j] = __builtin_amdgcn_mfma_f32_16x16x32_bf16(
                        af[i], bf4[j], acc[i][j], 0, 0, 0);
            __syncthreads();
        }
    }

    // C/D layout: col = lane&15, row = (lane>>4)*4 + reg
    float bv[4] = {0.f, 0.f, 0.f, 0.f};
    if (bias) {
#pragma unroll
        for (int j = 0; j < 4; ++j) bv[j] = bias[N0 + wn + j * 16 + lr];
    }
    if (fl & 1) {
        ushort_t* C = (ushort_t*)Cv + zb * sCb;
#pragma unroll
        for (int i = 0; i < 4; ++i)
#pragma unroll
            for (int r = 0; r < 4; ++r) {
                int row = M0 + wm + i * 16 + lq * 4 + r;
                ushort_t* cp = C + (long)row * ldc + N0 + wn + lr;
#pragma unroll
                for (int j = 0; j < 4; ++j)
                    cp[j * 16] = f2bf(alpha * acc[i][j][r] + add0 + bv[j]);
            }
    } else {
        if ((fl & 8) && wm) return;
        float* C = (float*)Cv + zb * sCb;
#pragma unroll
        for (int i = 0; i < 4; ++i)
#pragma unroll
            for (int r = 0; r < 4; ++r) {
                int row = M0 + wm + i * 16 + lq * 4 + r;
                float* cp = C + (long)row * ldc + N0 + wn + lr;
#pragma unroll
                for (int j = 0; j < 4; ++j) {
                    float val = alpha * acc[i][j][r] + add0 + bv[j];
                    if (fl & 4) val += cp[j * 16];
                    cp[j * 16] = val;
                }
            }
    }
}

// ---------- fused per-chunk solve: MFMA update + intra solve + silu, slab in LDS ----------
// Grid (4, 1, BATCH), 256 threads. Block owns a 64x256 slab of one batch:
//   phase 1 (c>0): acc = G[chunk rows, 0:K] @ E_prev (MFMA); Us = u_slab - acc (LDS)
//           (c==0): Us = u_slab
//   phase 2: unit-lower-triangular solve down the 64 rows (register recurrence on Us)
//   phase 3: emit EbT (transposed bf16) for later chunks (skipped for last chunk)
//   phase 4: fused silu: tgtb[row][j] = bf16(silu(e + tgt)) IN PLACE (tgtb becomes hb)
// Solved err is never written back to u — nothing downstream reads it.
__global__ __launch_bounds__(256) void solve_chunk(const float* __restrict__ u,
                                                   const ushort_t* __restrict__ gram,
                                                   ushort_t* __restrict__ ebt,
                                                   ushort_t* __restrict__ tgtb, int c)
{
    const int b = blockIdx.z;
    const int j0 = blockIdx.x << 8;          // 0,256,512,768
    const int t0 = c << 6;
    const int tid = threadIdx.x;
    const int wave = tid >> 6, lane = tid & 63;
    const int lr = lane & 15, lq = lane >> 4;

    __shared__ float Us[64][260];                       // 65 KB slab (stride 260: bank-rotate)
    __shared__ __align__(16) char smem2[4096 + 16384];  // As 4KB | Bs 16KB ; reused as Gs 16KB
    ushort_t* As = (ushort_t*)smem2;
    ushort_t* Bs = (ushort_t*)(smem2 + 4096);
    float* Gs = (float*)smem2;

    const ushort_t* Gb = gram + (long)b * SEQ * SEQ + (long)t0 * SEQ;   // 64 x SEQ chunk rows
    const float* Ub = u + (long)b * SEQ * ID + (long)t0 * ID;           // 64 x ID chunk slab
    ushort_t* Eb = ebt + (long)b * ID * SEQ;                            // ID x SEQ transposed E

    if (c > 0) {
        const int K = c << 6;
        floatx4 acc[4][4] = {};
        const ushort_t* ga = Gb + (long)(wave * 16 + (lane >> 2)) * SEQ + (lane & 3) * 8;
        const ushort_t* gb = Eb + (long)(j0 + wave * 16 + (lane >> 2)) * SEQ + (lane & 3) * 8;
        ushort_t* la  = &As[(wave * 16) * 32];
        ushort_t* lb0 = &Bs[(wave * 16)       * 32];
        ushort_t* lb1 = &Bs[(64  + wave * 16) * 32];
        ushort_t* lb2 = &Bs[(128 + wave * 16) * 32];
        ushort_t* lb3 = &Bs[(192 + wave * 16) * 32];
        for (int k0 = 0; k0 < K; k0 += 32) {
            load_lds16(ga, la);
            load_lds16(gb,              lb0);
            load_lds16(gb + 64L * SEQ,  lb1);
            load_lds16(gb + 128L * SEQ, lb2);
            load_lds16(gb + 192L * SEQ, lb3);
            ga += 32; gb += 32;
            __syncthreads();
            short8 af[4], bf4[4];
#pragma unroll
            for (int i = 0; i < 4; ++i)
                af[i] = *(const short8*)&As[(i * 16 + lr) * 32 + lq * 8];
#pragma unroll
            for (int j = 0; j < 4; ++j)
                bf4[j] = *(const short8*)&Bs[(wave * 64 + j * 16 + lr) * 32 + lq * 8];
#pragma unroll
            for (int i = 0; i < 4; ++i)
#pragma unroll
                for (int j = 0; j < 4; ++j)
                    acc[i][j] = __builtin_amdgcn_mfma_f32_16x16x32_bf16(
                        af[i], bf4[j], acc[i][j], 0, 0, 0);
            __syncthreads();
        }
        // Us = u_slab - acc   (C/D layout: col=lane&15, row=lq*4+reg)
#pragma unroll
        for (int i = 0; i < 4; ++i)
#pragma unroll
            for (int r = 0; r < 4; ++r) {
                int row = i * 16 + lq * 4 + r;
                const float* up = Ub + (long)row * ID + j0 + wave * 64 + lr;
#pragma unroll
                for (int j = 0; j < 4; ++j)
                    Us[row][wave * 64 + j * 16 + lr] = up[j * 16] - acc[i][j][r];
            }
    } else {
        // plain cooperative slab load (16 float4 per thread)
        for (int idx = tid; idx < 64 * 64; idx += 256) {
            int row = idx >> 6, col4 = (idx & 63) << 2;
            float4 v = *(const float4*)(Ub + (long)row * ID + j0 + col4);
            Us[row][col4 + 0] = v.x; Us[row][col4 + 1] = v.y;
            Us[row][col4 + 2] = v.z; Us[row][col4 + 3] = v.w;
        }
    }

    // stage G diag block (bf16 -> f32 LDS; overlays As/Bs — safe, past last read)
    for (int v = tid; v < 512; v += 256) {
        int row = v >> 3, col8 = (v & 7) << 3;
        ushort8 g8 = *(const ushort8*)(Gb + (long)row * SEQ + t0 + col8);
#pragma unroll
        for (int k = 0; k < 8; ++k) Gs[row * 64 + col8 + k] = bf2f(g8[k]);
    }
    __syncthreads();   // Us complete (all waves) + Gs complete

    // intra-chunk forward substitution, one column per thread (all LDS)
    float e[64];
    e[0] = Us[0][tid];
#pragma unroll
    for (int t = 1; t < 64; ++t) {
        float v = Us[t][tid];
        float p0 = 0.f, p1 = 0.f, p2 = 0.f, p3 = 0.f;   // 4-way ILP on the chain
#pragma unroll
        for (int s = 0; s + 3 < t; s += 4) {
            p0 = fmaf(Gs[t * 64 + s + 0], e[s + 0], p0);
            p1 = fmaf(Gs[t * 64 + s + 1], e[s + 1], p1);
            p2 = fmaf(Gs[t * 64 + s + 2], e[s + 2], p2);
            p3 = fmaf(Gs[t * 64 + s + 3], e[s + 3], p3);
        }
#pragma unroll
        for (int s = t & ~3; s < t; ++s)
            p0 = fmaf(Gs[t * 64 + s], e[s], p0);
        e[t] = v - ((p0 + p1) + (p2 + p3));
    }

    // transposed bf16 copy of the solved chunk for later chunks' MFMA updates
    if (c < NCHUNK - 1) {
        ushort_t* EB = Eb + (long)(j0 + tid) * SEQ + t0;
#pragma unroll
        for (int g = 0; g < 8; ++g) {
            ushort8 o;
#pragma unroll
            for (int k = 0; k < 8; ++k) o[k] = f2bf(e[g * 8 + k]);
            *(ushort8*)(EB + g * 8) = o;
        }
    }

    // fused silu, in place over tgtb (tgtb becomes hb)
    ushort_t* Tp = tgtb + ((long)b * SEQ + t0) * ID + j0 + tid;
#pragma unroll
    for (int t = 0; t < 64; ++t) {
        float v = e[t] + bf2f(Tp[(long)t * ID]);
        Tp[(long)t * ID] = f2bf(v / (1.0f + __expf(-v)));
    }
}

// ---------- gate + residual mix + LayerNorm (z, ttt in bf16) ----------
__global__ __launch_bounds__(256) void gate_ln(
    const ushort_t* __restrict__ zb, const ushort_t* __restrict__ tttb,
    const float* __restrict__ x, const float* __restrict__ gamma,
    const float* __restrict__ bet, float* __restrict__ out)
{
    long base = (long)blockIdx.x * HD + threadIdx.x * 4;
    ushort4v zv4 = *(const ushort4v*)(zb + base);
    ushort4v tv4 = *(const ushort4v*)(tttb + base);
    float4 xv = *(const float4*)(x + base);
    float xr[4] = {xv.x, xv.y, xv.z, xv.w};
    float y[4];
#pragma unroll
    for (int k = 0; k < 4; ++k) {
        float g = 1.0f / (1.0f + __expf(-bf2f(zv4[k])));
        float t = bf2f(tv4[k]);
        y[k] = g * t + (1.0f - g) * xr[k];
    }
    float sum = y[0] + y[1] + y[2] + y[3];
    float sq  = y[0]*y[0] + y[1]*y[1] + y[2]*y[2] + y[3]*y[3];
#pragma unroll
    for (int off = 32; off > 0; off >>= 1) {
        sum += __shfl_down(sum, off);
        sq  += __shfl_down(sq, off);
    }
    __shared__ float s1[4], s2[4];
    int wid = threadIdx.x >> 6;
    if ((threadIdx.x & 63) == 0) { s1[wid] = sum; s2[wid] = sq; }
    __syncthreads();
    float tot = s1[0] + s1[1] + s1[2] + s1[3];
    float tsq = s2[0] + s2[1] + s2[2] + s2[3];
    float mu = tot * (1.0f / HD);
    float var = tsq * (1.0f / HD) - mu * mu;
    float rs = rsqrtf(var + 1e-5f);
    int col = threadIdx.x * 4;
    float4 ov;
    ov.x = (y[0] - mu) * rs * gamma[col + 0] + bet[col + 0];
    ov.y = (y[1] - mu) * rs * gamma[col + 1] + bet[col + 1];
    ov.z = (y[2] - mu) * rs * gamma[col + 2] + bet[col + 2];
    ov.w = (y[3] - mu) * rs * gamma[col + 3] + bet[col + 3];
    *(float4*)(out + base) = ov;
}

extern "C" void kernel_launch(void* const* d_in, const int* in_sizes, int n_in,
                              void* d_out, int out_size, void* d_ws, size_t ws_size,
                              hipStream_t stream)
{
    const float* x    = (const float*)d_in[0];
    const float* Wi   = (const float*)d_in[1];
    const float* bi   = (const float*)d_in[2];
    const float* Wt   = (const float*)d_in[3];
    const float* bt   = (const float*)d_in[4];
    const float* Wo   = (const float*)d_in[5];
    const float* bo   = (const float*)d_in[6];
    const float* Wg   = (const float*)d_in[7];
    const float* bg   = (const float*)d_in[8];
    const float* gam  = (const float*)d_in[9];
    const float* bet  = (const float*)d_in[10];
    float* out = (float*)d_out;

    // Workspace ~394 MB (unchanged footprint):
    //   u    [BS,ID] f32 128MB : RHS (read-only during solve); AFTER solve reused as zb bf16
    //   tgtb [BS,ID] bf16 64MB : target; solve_chunk silu-rewrites IN PLACE -> becomes hb
    //   gram region       64MB : gramb bf16 [B,S,S] (32MB); dead after solve
    //   xb   [BS,HD] bf16 64MB : x bf16 (live until z GEMM)
    //   tttb [BS,HD] bf16 64MB : DURING solve overlaid by EbT bf16 [B,ID,SEQ]; after: ttt
    //   weights bf16 ~10MB + bd
    float* u       = (float*)d_ws;
    ushort_t* tgtb = (ushort_t*)(u + (long)BS * ID);
    float* gram    = (float*)(tgtb + (long)BS * ID);
    ushort_t* xb   = (ushort_t*)(gram + (long)BATCH * SEQ * SEQ);
    ushort_t* tttb = xb + (long)BS * HD;
    ushort_t* WdT  = tttb + (long)BS * HD;            // [ID,HD]
    ushort_t* WtT  = WdT + (long)HD * ID;             // [ID,HD]
    ushort_t* WoT  = WtT + (long)HD * ID;             // [HD,ID]
    ushort_t* WgT  = WoT + (long)HD * ID;             // [HD, 2*HD] concat K
    float* bd      = (float*)(WgT + (long)HD * 2 * HD);
    ushort_t* gramb = (ushort_t*)gram;                // gram stored bf16
    ushort_t* ebt   = (ushort_t*)tttb;                // overlay: EbT during solve
    ushort_t* hb    = tgtb;                           // after solve: silu output in place
    ushort_t* zb    = (ushort_t*)u;                   // overlay: after solve
    // ---- prep (3 launches) ----
    prep_w<<<dim3(32, 32), dim3(32, 8), 0, stream>>>(Wi, Wt, WdT, WtT, bi, bt, bd);
    prep_transposes<<<dim3(32, 32, 3), dim3(32, 8), 0, stream>>>(Wo, Wg, WoT, WgT);
    convert_bf16<<<16384, 256, 0, stream>>>(x, xb);

    dim3 gBig(ID / 128, BS / 128, 1);   // 8 x 256
    // DUAL: z=0: u = x @ (Wi - Wt) + (bi - bt) [f32]; z=1: target = x @ Wt + bt [bf16]
    gemm_bf16<<<dim3(ID / 128, BS / 128, 2), 256, 0, stream>>>(
        xb, 0, HD, nullptr, 0, 0, WdT, 0, HD,
        u, 0, ID, HD, bd, 1.f, 0.f, 16,
        WtT, tgtb, bt, 1);
    // gram = (LR/I) * (X X^T + 1)     [bf16 out, lower tiles only]
    gemm_bf16<<<dim3(SEQ / 128, SEQ / 128, BATCH), 256, 0, stream>>>(
        xb, (long)SEQ * HD, HD, nullptr, 0, 0, xb, (long)SEQ * HD, HD,
        gramb, (long)SEQ * SEQ, SEQ, HD, nullptr, LR_OVER_I, LR_OVER_I, 2 | 1,
        nullptr, nullptr, nullptr, 0);

    // ---- blocked forward substitution + fused silu (8 launches) ----
    for (int c = 0; c < NCHUNK; ++c)
        solve_chunk<<<dim3(4, 1, BATCH), 256, 0, stream>>>(u, gramb, ebt, tgtb, c);

    // ttt = h @ Wo + bo               [bf16 out; hb == tgtb in place]
    gemm_bf16<<<gBig, 256, 0, stream>>>(hb, 0, ID, nullptr, 0, 0, WoT, 0, ID,
                                        tttb, 0, HD, ID, bo, 1.f, 0.f, 1,
                                        nullptr, nullptr, nullptr, 0);
    // z = [x, ttt] @ Wg + bg          [bf16 out, two K-segments; zb overlays u]
    gemm_bf16<<<gBig, 256, 0, stream>>>(xb, 0, HD, tttb, 0, HD, WgT, 0, 2 * HD,
                                        zb, 0, HD, HD, bg, 1.f, 0.f, 1,
                                        nullptr, nullptr, nullptr, 0);
    // out = LN(g*ttt + (1-g)*x)
    gate_ln<<<BS, 256, 0, stream>>>(zb, tttb, x, gam, bet, out);
}